// Round 16
// baseline (238.058 us; speedup 1.0000x reference)
//
#include <hip/hip_runtime.h>
#include <hip/hip_bf16.h>

typedef unsigned short ushort;
typedef unsigned int uint;
typedef unsigned long long u64;
typedef _Float16 f16;

#define NN 4096
#define PP 128
#define QQ 128
#define HD 256
#define KH 8
#define DD 64
#define KK 16384  // P*Q

typedef _Float16 f16x2 __attribute__((ext_vector_type(2)));
typedef _Float16 f16x4 __attribute__((ext_vector_type(4)));
typedef _Float16 f16x8 __attribute__((ext_vector_type(8)));
typedef __fp16 fp16x2 __attribute__((ext_vector_type(2)));  // cvt_pkrtz return type
typedef float f32x4 __attribute__((ext_vector_type(4)));

__device__ inline void async_lds16(const void* g, void* l) {
  __builtin_amdgcn_global_load_lds(
      (const __attribute__((address_space(1))) unsigned int*)g,
      (__attribute__((address_space(3))) unsigned int*)l, 16, 0, 0);
}

// ---------------------------------------------------------------------------
// K0: split W and Wt fp32 -> f16 hi + f16 lo; also zero the x accumulator.
// ---------------------------------------------------------------------------
__global__ __launch_bounds__(256) void k0_split2(
    const float* __restrict__ W, const float* __restrict__ Wt,
    f16* __restrict__ hiW, f16* __restrict__ loW,
    f16* __restrict__ hiT, f16* __restrict__ loT, float* __restrict__ xz) {
  const int tid = blockIdx.x * 256 + threadIdx.x;
  const int i = tid * 4;
  if (tid < (NN * HD) / 4)
    *(float4*)&xz[i] = make_float4(0.f, 0.f, 0.f, 0.f);
  const float* src;
  f16 *hi, *lo;
  int off;
  if (i < HD * PP * QQ) { src = W; hi = hiW; lo = loW; off = i; }
  else { src = Wt; hi = hiT; lo = loT; off = i - HD * PP * QQ; }
  const float4 w = *(const float4*)&src[off];
  const float wf[4] = {w.x, w.y, w.z, w.w};
  f16x4 hv, lv;
#pragma unroll
  for (int j = 0; j < 4; ++j) {
    const f16 h = (f16)wf[j];
    hv[j] = h;
    lv[j] = (f16)(wf[j] - (float)h);
  }
  *(f16x4*)&hi[off] = hv;
  *(f16x4*)&lo[off] = lv;
}

// ---------------------------------------------------------------------------
// K1 (R9 structure, best verified ~108-110 µs): R6 structure + 2-deep W DMA
// pipeline. DMA(c+1) issues at top of step c into a double buffer; both
// barriers are lgkm-only; DMA(c) retirement enforced by the compiler's
// precise vmcnt before z-form(c)'s xn use. LDS = 40960 B -> 4 blocks/CU.
// k1 restructuring CLOSED (R1/R2/R4/R7/R8/R10 + T5 all lost to this).
// ---------------------------------------------------------------------------
__global__ __launch_bounds__(256, 4) void k1_bilinear(
    const float* __restrict__ xp, const float* __restrict__ xn,
    const f16* __restrict__ Whi, const f16* __restrict__ Wlo,
    float* __restrict__ xout) {
  __shared__ f16 whi[2][128 * 32];   // [h][k], XOR-swizzled 16B segs (2x8 KB)
  __shared__ f16 wlo[2][128 * 32];   // 2x8 KB
  __shared__ f16 zhi[128 * 32];      // [n][k], XOR-swizzled (8 KB)  -> 40960 B

  const int t = threadIdx.x;
  // XCD-panel-affine decode (R5): bid%8 = XCD under round-robin dispatch.
  const int bid = blockIdx.x;
  const int xcd = bid & 7, slot = bid >> 3;
  const int jpan = slot >> 5, n_idx = slot & 31;
  const int pan = xcd + 8 * jpan;          // 0..31
  const int n0 = n_idx * 128;
  const int kb = (pan & 15) * (KK / 16);   // 1024-wide K chunk
  const int h0 = (pan >> 4) * 128;
  const int pb = kb >> 7;                  // 8 p values per block

  const int l = t & 63, w = t >> 6;
  const int wr = (w >> 1) * 64, wc = (w & 1) * 64;

  int aoff[4], boff[4];
#pragma unroll
  for (int i = 0; i < 4; ++i) {
    const int row = wr + i * 16 + (l & 15);
    aoff[i] = row * 32 + (((l >> 4) ^ ((row ^ (row >> 2)) & 3)) * 8);
  }
#pragma unroll
  for (int j = 0; j < 4; ++j) {
    const int hr = wc + j * 16 + (l & 15);
    boff[j] = hr * 32 + (((l >> 4) ^ ((hr ^ (hr >> 2)) & 3)) * 8);
  }

  // W staging: 128 rows x 4 segs = 512 slots; 256 thr -> 2 row-groups of 64
  const int shb = t >> 2, seg = t & 3;
  int gsw[2];
#pragma unroll
  for (int g = 0; g < 2; ++g) {
    const int r = shb + 64 * g;
    gsw[g] = seg ^ ((r ^ (r >> 2)) & 3);
  }

  auto stage_w = [&](int buf, int kc_) {
#pragma unroll
    for (int g = 0; g < 2; ++g) {
      const int r = shb + 64 * g;
      async_lds16(Whi + (size_t)(h0 + r) * KK + kc_ + gsw[g] * 8,
                  &whi[buf][r * 32 + seg * 8]);
      async_lds16(Wlo + (size_t)(h0 + r) * KK + kc_ + gsw[g] * 8,
                  &wlo[buf][r * 32 + seg * 8]);
    }
  };

  const int zn = t >> 1, zko = (t & 1) * 16;
  const int zm = (zn ^ (zn >> 2)) & 3;
  const int zs0 = (t & 1) * 2;
  const int zo0 = zn * 32 + ((zs0 ^ zm) * 8);
  const int zo1 = zn * 32 + (((zs0 + 1) ^ zm) * 8);

  f32x4 acc[4][4];
#pragma unroll
  for (int i = 0; i < 4; ++i)
#pragma unroll
    for (int j = 0; j < 4; ++j) acc[i][j] = (f32x4)0.f;

  // ---- prologue: xp->regs, xn(0)->regs, DMA(0), one full drain ----
  float xpp[8];
  {
    const float* xpr = xp + (size_t)(n0 + zn) * PP + pb;
    const f32x4 a = *(const f32x4*)xpr;
    const f32x4 b = *(const f32x4*)(xpr + 4);
    xpp[0] = a[0]; xpp[1] = a[1]; xpp[2] = a[2]; xpp[3] = a[3];
    xpp[4] = b[0]; xpp[5] = b[1]; xpp[6] = b[2]; xpp[7] = b[3];
  }
  const float* xrow = xn + (size_t)(n0 + zn) * QQ + zko;
  float4 xv0 = ((const float4*)xrow)[0];
  float4 xv1 = ((const float4*)xrow)[1];
  float4 xv2 = ((const float4*)xrow)[2];
  float4 xv3 = ((const float4*)xrow)[3];
  stage_w(0, kb);
  __syncthreads();  // single full drain; loop barriers are lgkm-only

#pragma unroll
  for (int pl = 0; pl < 8; ++pl) {
#pragma unroll 1
    for (int q = 0; q < 4; ++q) {
      const int c = pl * 4 + q;
      const int cur = c & 1;
      const bool more = (pl < 7) || (q < 3);  // pl folds at unroll

      // Barrier A: prev step's fragment ds_reads drained; W DMA stays
      // in flight across it (lgkm-only).
      asm volatile("s_waitcnt lgkmcnt(0)" ::: "memory");
      __builtin_amdgcn_sched_barrier(0);
      __builtin_amdgcn_s_barrier();
      __builtin_amdgcn_sched_barrier(0);

      // Issue DMA for step c+1 into the other buffer (WAR-safe: that
      // buffer's last reads were step c-1's, drained by barrier A).
      if (more) stage_w(cur ^ 1, kb + (c + 1) * 32);

      // z-form from prefetched xn regs. The compiler's wait for the xn
      // loads here retires DMA(c) (older) and leaves DMA(c+1) (newer)
      // in flight -> DMA(c) got a full step of cover.
      {
        const float xpv = xpp[pl];  // static index (pl unrolled)
        float zz[16] = {xv0.x, xv0.y, xv0.z, xv0.w, xv1.x, xv1.y, xv1.z, xv1.w,
                        xv2.x, xv2.y, xv2.z, xv2.w, xv3.x, xv3.y, xv3.z, xv3.w};
        union { uint u[8]; uint4 qd[2]; } ph;
#pragma unroll
        for (int j = 0; j < 8; ++j) {
          union { fp16x2 h; uint u; } cv;
          cv.h = __builtin_amdgcn_cvt_pkrtz(xpv * zz[2 * j], xpv * zz[2 * j + 1]);
          ph.u[j] = cv.u;
        }
        *(uint4*)&zhi[zo0] = ph.qd[0];
        *(uint4*)&zhi[zo1] = ph.qd[1];
      }

      // Barrier B: z ds_writes visible; W(c) already retired above.
      asm volatile("s_waitcnt lgkmcnt(0)" ::: "memory");
      __builtin_amdgcn_sched_barrier(0);
      __builtin_amdgcn_s_barrier();
      __builtin_amdgcn_sched_barrier(0);

      // xn prefetch for step c+1 (issued under this step's MFMA phase).
      if (more) {
        const int qn = ((c + 1) & 3) * 32;
        xv0 = ((const float4*)(xrow + qn))[0];
        xv1 = ((const float4*)(xrow + qn))[1];
        xv2 = ((const float4*)(xrow + qn))[2];
        xv3 = ((const float4*)(xrow + qn))[3];
      }

      f16x8 Ah[4];
#pragma unroll
      for (int i = 0; i < 4; ++i) Ah[i] = *(const f16x8*)&zhi[aoff[i]];
#pragma unroll
      for (int j = 0; j < 4; ++j) {
        const f16x8 Bh = *(const f16x8*)&whi[cur][boff[j]];
        const f16x8 Bl = *(const f16x8*)&wlo[cur][boff[j]];
#pragma unroll
        for (int i = 0; i < 4; ++i)
          acc[i][j] = __builtin_amdgcn_mfma_f32_16x16x32_f16(Ah[i], Bh, acc[i][j], 0, 0, 0);
#pragma unroll
        for (int i = 0; i < 4; ++i)
          acc[i][j] = __builtin_amdgcn_mfma_f32_16x16x32_f16(Ah[i], Bl, acc[i][j], 0, 0, 0);
      }
    }
  }

#pragma unroll
  for (int i = 0; i < 4; ++i)
#pragma unroll
    for (int j = 0; j < 4; ++j) {
      const int row = n0 + wr + i * 16 + (l >> 4) * 4;
      const int col = h0 + wc + j * 16 + (l & 15);
#pragma unroll
      for (int r = 0; r < 4; ++r)
        atomicAdd(&xout[(size_t)(row + r) * HD + col], acc[i][j][r]);
    }
}

// ---------------------------------------------------------------------------
// K23: xt[k][n][d] = sum_h (x[n][h]+b[h]) * (Wthi+Wtlo)[k*64+d][h]
// 2-pass fp16 MFMA; bias+cvt fused in A-stage; u/v dots fused in epilogue.
// ---------------------------------------------------------------------------
__global__ __launch_bounds__(256) void k23_xt(
    const float* __restrict__ x, const float* __restrict__ bb,
    const f16* __restrict__ Wthi, const f16* __restrict__ Wtlo,
    const float* __restrict__ av, float* __restrict__ xt,
    float* __restrict__ ssrc, float* __restrict__ sdst) {
  __shared__ f16 ah[64 * 32];
  __shared__ f16 bh[128 * 32];
  __shared__ f16 bl[128 * 32];
  __shared__ float red1[2][64][17];
  __shared__ float red2[2][64][17];
  const int t = threadIdx.x;
  const int n0 = blockIdx.x * 64;
  const int c0 = blockIdx.y * 128;
  const int l = t & 63, w = t >> 6;
  const int wn = (w & 1) * 32, wcc = (w >> 1) * 64;

  int aoff[2], boff[4];
#pragma unroll
  for (int i = 0; i < 2; ++i) {
    const int row = wn + i * 16 + (l & 15);
    aoff[i] = row * 32 + (((l >> 4) ^ ((row ^ (row >> 2)) & 3)) * 8);
  }
#pragma unroll
  for (int j = 0; j < 4; ++j) {
    const int hr = wcc + j * 16 + (l & 15);
    boff[j] = hr * 32 + (((l >> 4) ^ ((hr ^ (hr >> 2)) & 3)) * 8);
  }

  f32x4 acc[2][4];
#pragma unroll
  for (int i = 0; i < 2; ++i)
#pragma unroll
    for (int j = 0; j < 4; ++j) acc[i][j] = (f32x4)0.f;

  for (int kc = 0; kc < HD; kc += 32) {
    __syncthreads();
    {  // A stage: read x fp32 + bias, cvt f16, store 16B (swizzled seg)
      const int row = t >> 2, sg = t & 3;
      const float* xr = &x[(size_t)(n0 + row) * HD + kc + sg * 8];
      const float4 xa = ((const float4*)xr)[0];
      const float4 xb = ((const float4*)xr)[1];
      const float4 ba = *(const float4*)&bb[kc + sg * 8];
      const float4 bv = *(const float4*)&bb[kc + sg * 8 + 4];
      f16x8 o;
      o[0] = (f16)(xa.x + ba.x); o[1] = (f16)(xa.y + ba.y);
      o[2] = (f16)(xa.z + ba.z); o[3] = (f16)(xa.w + ba.w);
      o[4] = (f16)(xb.x + bv.x); o[5] = (f16)(xb.y + bv.y);
      o[6] = (f16)(xb.z + bv.z); o[7] = (f16)(xb.w + bv.w);
      const int sgs = sg ^ ((row ^ (row >> 2)) & 3);
      *(f16x8*)&ah[row * 32 + sgs * 8] = o;
    }
#pragma unroll
    for (int g = 0; g < 2; ++g) {  // B stage: 128 cols x 4 segs = 512 slots
      const int slot = g * 256 + t;
      const int col = slot >> 2, ps = slot & 3;
      const int ls = ps ^ ((col ^ (col >> 2)) & 3);
      *(uint4*)&bh[col * 32 + ps * 8] =
          *(const uint4*)&Wthi[(size_t)(c0 + col) * HD + kc + ls * 8];
      *(uint4*)&bl[col * 32 + ps * 8] =
          *(const uint4*)&Wtlo[(size_t)(c0 + col) * HD + kc + ls * 8];
    }
    __syncthreads();
    f16x8 Af[2];
#pragma unroll
    for (int i = 0; i < 2; ++i) Af[i] = *(const f16x8*)&ah[aoff[i]];
#pragma unroll
    for (int j = 0; j < 4; ++j) {
      const f16x8 Bh = *(const f16x8*)&bh[boff[j]];
      const f16x8 Bl = *(const f16x8*)&bl[boff[j]];
#pragma unroll
      for (int i = 0; i < 2; ++i)
        acc[i][j] = __builtin_amdgcn_mfma_f32_16x16x32_f16(Af[i], Bh, acc[i][j], 0, 0, 0);
#pragma unroll
      for (int i = 0; i < 2; ++i)
        acc[i][j] = __builtin_amdgcn_mfma_f32_16x16x32_f16(Af[i], Bl, acc[i][j], 0, 0, 0);
    }
  }

  const int hh = w >> 1;
  const int khead = (c0 >> 6) + hh;
  float a1v[4], a2v[4];
#pragma unroll
  for (int j = 0; j < 4; ++j) {
    const int d = j * 16 + (l & 15);
    a1v[j] = av[khead * (2 * DD) + d];
    a2v[j] = av[khead * (2 * DD) + DD + d];
  }

#pragma unroll
  for (int i = 0; i < 2; ++i)
#pragma unroll
    for (int r = 0; r < 4; ++r) {
      const int rowl = wn + i * 16 + (l >> 4) * 4 + r;
      float p1 = 0.f, p2 = 0.f;
#pragma unroll
      for (int j = 0; j < 4; ++j) {
        p1 += acc[i][j][r] * a1v[j];
        p2 += acc[i][j][r] * a2v[j];
      }
      red1[hh][rowl][l & 15] = p1;
      red2[hh][rowl][l & 15] = p2;
    }

#pragma unroll
  for (int i = 0; i < 2; ++i)
#pragma unroll
    for (int j = 0; j < 4; ++j) {
      const int row = n0 + wn + i * 16 + (l >> 4) * 4;
      const int colg = c0 + wcc + j * 16 + (l & 15);
      const int k = colg >> 6, d = colg & 63;
#pragma unroll
      for (int r = 0; r < 4; ++r)
        xt[((size_t)(k * NN + row + r)) * DD + d] = acc[i][j][r];
    }

  __syncthreads();
  {
    const int hh2 = t >> 7;
    const int which = (t >> 6) & 1;
    const int row = t & 63;
    const float* rp = which ? &red2[hh2][row][0] : &red1[hh2][row][0];
    float s = 0.f;
#pragma unroll
    for (int g = 0; g < 16; ++g) s += rp[g];
    const int kk = (c0 >> 6) + hh2;
    if (which) sdst[kk * NN + n0 + row] = s;
    else ssrc[kk * NN + n0 + row] = s;
  }
}

// ---------------------------------------------------------------------------
// K4a: rank-and-scatter "sort" (exact total order via packed u64 keys).
// R11: grid (64,KH), 64 m/block, 4 threads per m each counting a 1024-wide
// j-quarter; partials summed in LDS. Bit-identical ranks.
// ---------------------------------------------------------------------------
__global__ __launch_bounds__(256) void k4_rank(
    const float* __restrict__ sdst, float* __restrict__ vsorted,
    int* __restrict__ perm) {
  __shared__ u64 kv[4096];
  __shared__ ushort pcnt[256];
  const int k = blockIdx.y, t = threadIdx.x;
  for (int i = t; i < 4096; i += 256) {
    const uint u = __float_as_uint(sdst[k * NN + i]);
    const uint key = (u & 0x80000000u) ? ~u : (u | 0x80000000u);
    kv[i] = ((u64)key << 32) | (uint)i;
  }
  __syncthreads();
  const int idx = t & 63;           // local m index (0..63)
  const int qtr = t >> 6;           // j-quarter this thread scans
  const u64 my = kv[blockIdx.x * 64 + idx];
  const int j0 = qtr * 1024;
  int cnt = 0;
#pragma unroll 16
  for (int j = 0; j < 1024; ++j) cnt += (kv[j0 + j] < my) ? 1 : 0;
  pcnt[t] = (ushort)cnt;
  __syncthreads();
  if (t < 64) {
    const int tot = (int)pcnt[t] + (int)pcnt[t + 64] + (int)pcnt[t + 128] +
                    (int)pcnt[t + 192];
    const u64 my2 = kv[blockIdx.x * 64 + t];
    const uint key = (uint)(my2 >> 32);
    const uint u = (key & 0x80000000u) ? (key ^ 0x80000000u) : ~key;
    vsorted[k * NN + tot] = __uint_as_float(u);
    perm[k * NN + tot] = (int)(my2 & 0xFFFFFFFFu);
  }
}

// ---------------------------------------------------------------------------
// K4b: per-(head,chunk) sums; LDS-staged gather + shared exp precompute.
// ---------------------------------------------------------------------------
__global__ __launch_bounds__(64) void k4b_chunksum(
    const float* __restrict__ vs, const int* __restrict__ perm,
    const float* __restrict__ xt, float* __restrict__ Chi, float* __restrict__ Clo) {
  __shared__ float rows[64][64];
  __shared__ float eh[64], el[64];
  const int c = blockIdx.x, k = blockIdx.y, t = threadIdx.x;
  const int base = k * NN + c * 64;
  {
    const float v = vs[base + t];
    eh[t] = __expf(v);
    el[t] = __expf(0.2f * v);
  }
#pragma unroll
  for (int r = 0; r < 16; ++r) {
    const int i = r * 4 + (t >> 4);
    const int p = perm[base + i];
    *(float4*)&rows[i][(t & 15) * 4] =
        *(const float4*)&xt[((size_t)(k * NN + p)) * DD + (t & 15) * 4];
  }
  __syncthreads();
  float shi = 0.f, slo = 0.f, whs = 0.f, wls = 0.f;
#pragma unroll 8
  for (int i = 0; i < 64; ++i) {
    const float val = rows[i][t];
    shi += eh[i] * val; slo += el[i] * val;
    whs += eh[i]; wls += el[i];
  }
  const int cb = (k * 64 + c) * 65;
  Chi[cb + t] = shi;
  Clo[cb + t] = slo;
  if (t == 0) { Chi[cb + 64] = whs; Clo[cb + 64] = wls; }
}

// ---------------------------------------------------------------------------
// K4d (R11): prefix+suffix merged into one 128-thread block (wave0 = prefix/
// Plo with el, wave1 = suffix/Phi with eh). Shares the rows[] gather and the
// chunk-sum staging. Per-output arithmetic and order identical.
// ---------------------------------------------------------------------------
__global__ __launch_bounds__(128) void k4d_expand(
    const float* __restrict__ vs, const int* __restrict__ perm,
    const float* __restrict__ xt, const float* __restrict__ Chi,
    const float* __restrict__ Clo, float* __restrict__ Phi,
    float* __restrict__ Plo) {
  __shared__ float schi[64 * 65];
  __shared__ float sclo[64 * 65];
  __shared__ float rows[64][64];
  __shared__ float eh[64], el[64];
  const int c = blockIdx.x, k = blockIdx.y, t = threadIdx.x;
  const int base = k * NN + c * 64;
  for (int idx = t; idx < 4160; idx += 128) {
    schi[idx] = Chi[k * 4160 + idx];
    sclo[idx] = Clo[k * 4160 + idx];
  }
  if (t < 64) {
    const float v = vs[base + t];
    eh[t] = __expf(v);
    el[t] = __expf(0.2f * v);
  }
#pragma unroll
  for (int r = 0; r < 8; ++r) {
    const int i = r * 8 + (t >> 4);
    const int p = perm[base + i];
    *(float4*)&rows[i][(t & 15) * 4] =
        *(const float4*)&xt[((size_t)(k * NN + p)) * DD + (t & 15) * 4];
  }
  __syncthreads();

  if (t < 64) {  // wave 0: prefix pass -> Plo
    const int tt = t;
    float run = 0.f, wrun = 0.f;
    for (int cc = 0; cc < c; ++cc) {
      run += sclo[cc * 65 + tt];
      wrun += sclo[cc * 65 + 64];
    }
    for (int i = 0; i < 64; ++i) {
      const size_t rb = ((size_t)(k * 4097) + c * 64 + i) * 65;
      Plo[rb + tt] = run;
      if (tt == 0) Plo[rb + 64] = wrun;
      run += el[i] * rows[i][tt];
      wrun += el[i];
    }
    if (c == 63) {
      const size_t rb = ((size_t)(k * 4097) + 4096) * 65;
      Plo[rb + tt] = run;
      if (tt == 0) Plo[rb + 64] = wrun;
    }
  } else {  // wave 1: suffix pass -> Phi
    const int tt = t - 64;
    float runS = 0.f, wrunS = 0.f;
    for (int cc = c + 1; cc < 64; ++cc) {
      runS += schi[cc * 65 + tt];
      wrunS += schi[cc * 65 + 64];
    }
    for (int i = 63; i >= 0; --i) {
      runS += eh[i] * rows[i][tt];
      wrunS += eh[i];
      const size_t rb = ((size_t)(k * 4097) + c * 64 + i) * 65;
      Phi[rb + tt] = runS;
      if (tt == 0) Phi[rb + 64] = wrunS;
    }
    if (c == 63) {
      const size_t rb = ((size_t)(k * 4097) + 4096) * 65;
      Phi[rb + tt] = 0.f;
      if (tt == 0) Phi[rb + 64] = 0.f;
    }
  }
}

// ---------------------------------------------------------------------------
// K6 (R11): 32 queries/block — verified optimum of the staging/parallelism
// trade (64q at 512 blocks = 2/CU regressed; 16q doubles staging traffic).
// ---------------------------------------------------------------------------
__global__ __launch_bounds__(256) void k6_final(
    const float* __restrict__ ssrc, const float* __restrict__ vsorted,
    const float* __restrict__ Phi, const float* __restrict__ Plo,
    float* __restrict__ out) {
  __shared__ float vsh[4096];
  __shared__ int posSh[32];
  const int t = threadIdx.x;
  const int q0 = blockIdx.x * 32;
  const int k = q0 >> 12;
  for (int idx = t; idx < 1024; idx += 256)
    *(float4*)&vsh[idx * 4] = *(const float4*)&vsorted[k * NN + idx * 4];
  __syncthreads();
  if (t < 32) {
    const float thr = -ssrc[q0 + t];
    int lo = 0, hi = 4096;
    while (lo < hi) {
      const int mid = (lo + hi) >> 1;
      if (vsh[mid] < thr) lo = mid + 1; else hi = mid;
    }
    posSh[t] = lo;
  }
  __syncthreads();
  const int d = t & 63;
#pragma unroll
  for (int qq = 0; qq < 8; ++qq) {
    const int ql = qq * 4 + (t >> 6);
    const int qi = q0 + ql;
    const int n = qi & 4095;
    const float u = ssrc[qi];
    const size_t rb = ((size_t)(k * 4097) + posSh[ql]) * 65;
    const float eu = __expf(u), el = __expf(0.2f * u);
    const float num = eu * Phi[rb + d] + el * Plo[rb + d];
    const float den = eu * Phi[rb + 64] + el * Plo[rb + 64];
    out[(size_t)n * (KH * DD) + k * DD + d] = tanhf(num / den);
  }
}

extern "C" void kernel_launch(void* const* d_in, const int* in_sizes, int n_in,
                              void* d_out, int out_size, void* d_ws, size_t ws_size,
                              hipStream_t stream) {
  const float* xp = (const float*)d_in[0];
  const float* xn = (const float*)d_in[1];
  const float* W = (const float*)d_in[2];
  const float* bb = (const float*)d_in[3];
  const float* Wt = (const float*)d_in[4];
  const float* av = (const float*)d_in[5];
  float* out = (float*)d_out;

  char* ws = (char*)d_ws;
  // Phi/Plo overlay the W splits (temporally disjoint).
  f16* Whi    = (f16*)(ws);                       // 8 MB
  f16* Wlo    = (f16*)(ws + 8388608);             // 8 MB
  float* Phi  = (float*)(ws);                     // 8.52 MB (overlay)
  float* Plo  = (float*)(ws + 8522240);           // 8.52 MB (overlay)
  float* x    = (float*)(ws + 17044480);          // 4 MB
  float* xt   = (float*)(ws + 21238784);          // 8 MB
  f16* Wthi   = (f16*)(ws + 31724544);            // 256 KB
  f16* Wtlo   = (f16*)(ws + 31986688);            // 256 KB
  float* ssrc = (float*)(ws + 32248832);          // 128 KB
  float* sdst = (float*)(ws + 32379904);          // 128 KB
  float* vsort= (float*)(ws + 32510976);          // 128 KB
  int*   perm = (int*)  (ws + 32642048);          // 128 KB
  float* Chi  = (float*)(ws + 32773120);          // 133 KB
  float* Clo  = (float*)(ws + 32906240);          // 133 KB -> ends ~33.0 MB

  k0_split2<<<(HD * PP * QQ + KH * DD * HD) / 1024, 256, 0, stream>>>(
      W, Wt, Whi, Wlo, Wthi, Wtlo, x);
  k1_bilinear<<<1024, 256, 0, stream>>>(xp, xn, Whi, Wlo, x);
  k23_xt<<<dim3(NN / 64, 4), 256, 0, stream>>>(x, bb, Wthi, Wtlo, av, xt, ssrc, sdst);
  k4_rank<<<dim3(64, KH), 256, 0, stream>>>(sdst, vsort, perm);
  k4b_chunksum<<<dim3(64, KH), 64, 0, stream>>>(vsort, perm, xt, Chi, Clo);
  k4d_expand<<<dim3(64, KH), 128, 0, stream>>>(vsort, perm, xt, Chi, Clo, Phi, Plo);
  k6_final<<<(KH * NN) / 32, 256, 0, stream>>>(ssrc, vsort, Phi, Plo, out);
}

// Round 17
// 235.189 us; speedup vs baseline: 1.0122x; 1.0122x over previous
//
#include <hip/hip_runtime.h>
#include <hip/hip_bf16.h>

typedef unsigned short ushort;
typedef unsigned int uint;
typedef unsigned long long u64;
typedef _Float16 f16;

#define NN 4096
#define PP 128
#define QQ 128
#define HD 256
#define KH 8
#define DD 64
#define KK 16384  // P*Q

typedef _Float16 f16x2 __attribute__((ext_vector_type(2)));
typedef _Float16 f16x4 __attribute__((ext_vector_type(4)));
typedef _Float16 f16x8 __attribute__((ext_vector_type(8)));
typedef __fp16 fp16x2 __attribute__((ext_vector_type(2)));  // cvt_pkrtz return type
typedef float f32x4 __attribute__((ext_vector_type(4)));

__device__ inline void async_lds16(const void* g, void* l) {
  __builtin_amdgcn_global_load_lds(
      (const __attribute__((address_space(1))) unsigned int*)g,
      (__attribute__((address_space(3))) unsigned int*)l, 16, 0, 0);
}

// ---------------------------------------------------------------------------
// K0: split W and Wt fp32 -> f16 hi + f16 lo; also zero the x accumulator.
// ---------------------------------------------------------------------------
__global__ __launch_bounds__(256) void k0_split2(
    const float* __restrict__ W, const float* __restrict__ Wt,
    f16* __restrict__ hiW, f16* __restrict__ loW,
    f16* __restrict__ hiT, f16* __restrict__ loT, float* __restrict__ xz) {
  const int tid = blockIdx.x * 256 + threadIdx.x;
  const int i = tid * 4;
  if (tid < (NN * HD) / 4)
    *(float4*)&xz[i] = make_float4(0.f, 0.f, 0.f, 0.f);
  const float* src;
  f16 *hi, *lo;
  int off;
  if (i < HD * PP * QQ) { src = W; hi = hiW; lo = loW; off = i; }
  else { src = Wt; hi = hiT; lo = loT; off = i - HD * PP * QQ; }
  const float4 w = *(const float4*)&src[off];
  const float wf[4] = {w.x, w.y, w.z, w.w};
  f16x4 hv, lv;
#pragma unroll
  for (int j = 0; j < 4; ++j) {
    const f16 h = (f16)wf[j];
    hv[j] = h;
    lv[j] = (f16)(wf[j] - (float)h);
  }
  *(f16x4*)&hi[off] = hv;
  *(f16x4*)&lo[off] = lv;
}

// ---------------------------------------------------------------------------
// K1 (R9 structure, best verified ~108-110 µs): R6 structure + 2-deep W DMA
// pipeline. DMA(c+1) issues at top of step c into a double buffer; both
// barriers are lgkm-only; DMA(c) retirement enforced by the compiler's
// precise vmcnt before z-form(c)'s xn use. LDS = 40960 B -> 4 blocks/CU.
// k1 restructuring CLOSED (R1/R2/R4/R7/R8/R10 + T5 all lost to this).
// ---------------------------------------------------------------------------
__global__ __launch_bounds__(256, 4) void k1_bilinear(
    const float* __restrict__ xp, const float* __restrict__ xn,
    const f16* __restrict__ Whi, const f16* __restrict__ Wlo,
    float* __restrict__ xout) {
  __shared__ f16 whi[2][128 * 32];   // [h][k], XOR-swizzled 16B segs (2x8 KB)
  __shared__ f16 wlo[2][128 * 32];   // 2x8 KB
  __shared__ f16 zhi[128 * 32];      // [n][k], XOR-swizzled (8 KB)  -> 40960 B

  const int t = threadIdx.x;
  // XCD-panel-affine decode (R5): bid%8 = XCD under round-robin dispatch.
  const int bid = blockIdx.x;
  const int xcd = bid & 7, slot = bid >> 3;
  const int jpan = slot >> 5, n_idx = slot & 31;
  const int pan = xcd + 8 * jpan;          // 0..31
  const int n0 = n_idx * 128;
  const int kb = (pan & 15) * (KK / 16);   // 1024-wide K chunk
  const int h0 = (pan >> 4) * 128;
  const int pb = kb >> 7;                  // 8 p values per block

  const int l = t & 63, w = t >> 6;
  const int wr = (w >> 1) * 64, wc = (w & 1) * 64;

  int aoff[4], boff[4];
#pragma unroll
  for (int i = 0; i < 4; ++i) {
    const int row = wr + i * 16 + (l & 15);
    aoff[i] = row * 32 + (((l >> 4) ^ ((row ^ (row >> 2)) & 3)) * 8);
  }
#pragma unroll
  for (int j = 0; j < 4; ++j) {
    const int hr = wc + j * 16 + (l & 15);
    boff[j] = hr * 32 + (((l >> 4) ^ ((hr ^ (hr >> 2)) & 3)) * 8);
  }

  // W staging: 128 rows x 4 segs = 512 slots; 256 thr -> 2 row-groups of 64
  const int shb = t >> 2, seg = t & 3;
  int gsw[2];
#pragma unroll
  for (int g = 0; g < 2; ++g) {
    const int r = shb + 64 * g;
    gsw[g] = seg ^ ((r ^ (r >> 2)) & 3);
  }

  auto stage_w = [&](int buf, int kc_) {
#pragma unroll
    for (int g = 0; g < 2; ++g) {
      const int r = shb + 64 * g;
      async_lds16(Whi + (size_t)(h0 + r) * KK + kc_ + gsw[g] * 8,
                  &whi[buf][r * 32 + seg * 8]);
      async_lds16(Wlo + (size_t)(h0 + r) * KK + kc_ + gsw[g] * 8,
                  &wlo[buf][r * 32 + seg * 8]);
    }
  };

  const int zn = t >> 1, zko = (t & 1) * 16;
  const int zm = (zn ^ (zn >> 2)) & 3;
  const int zs0 = (t & 1) * 2;
  const int zo0 = zn * 32 + ((zs0 ^ zm) * 8);
  const int zo1 = zn * 32 + (((zs0 + 1) ^ zm) * 8);

  f32x4 acc[4][4];
#pragma unroll
  for (int i = 0; i < 4; ++i)
#pragma unroll
    for (int j = 0; j < 4; ++j) acc[i][j] = (f32x4)0.f;

  // ---- prologue: xp->regs, xn(0)->regs, DMA(0), one full drain ----
  float xpp[8];
  {
    const float* xpr = xp + (size_t)(n0 + zn) * PP + pb;
    const f32x4 a = *(const f32x4*)xpr;
    const f32x4 b = *(const f32x4*)(xpr + 4);
    xpp[0] = a[0]; xpp[1] = a[1]; xpp[2] = a[2]; xpp[3] = a[3];
    xpp[4] = b[0]; xpp[5] = b[1]; xpp[6] = b[2]; xpp[7] = b[3];
  }
  const float* xrow = xn + (size_t)(n0 + zn) * QQ + zko;
  float4 xv0 = ((const float4*)xrow)[0];
  float4 xv1 = ((const float4*)xrow)[1];
  float4 xv2 = ((const float4*)xrow)[2];
  float4 xv3 = ((const float4*)xrow)[3];
  stage_w(0, kb);
  __syncthreads();  // single full drain; loop barriers are lgkm-only

#pragma unroll
  for (int pl = 0; pl < 8; ++pl) {
#pragma unroll 1
    for (int q = 0; q < 4; ++q) {
      const int c = pl * 4 + q;
      const int cur = c & 1;
      const bool more = (pl < 7) || (q < 3);  // pl folds at unroll

      // Barrier A: prev step's fragment ds_reads drained; W DMA stays
      // in flight across it (lgkm-only).
      asm volatile("s_waitcnt lgkmcnt(0)" ::: "memory");
      __builtin_amdgcn_sched_barrier(0);
      __builtin_amdgcn_s_barrier();
      __builtin_amdgcn_sched_barrier(0);

      // Issue DMA for step c+1 into the other buffer (WAR-safe: that
      // buffer's last reads were step c-1's, drained by barrier A).
      if (more) stage_w(cur ^ 1, kb + (c + 1) * 32);

      // z-form from prefetched xn regs. The compiler's wait for the xn
      // loads here retires DMA(c) (older) and leaves DMA(c+1) (newer)
      // in flight -> DMA(c) got a full step of cover.
      {
        const float xpv = xpp[pl];  // static index (pl unrolled)
        float zz[16] = {xv0.x, xv0.y, xv0.z, xv0.w, xv1.x, xv1.y, xv1.z, xv1.w,
                        xv2.x, xv2.y, xv2.z, xv2.w, xv3.x, xv3.y, xv3.z, xv3.w};
        union { uint u[8]; uint4 qd[2]; } ph;
#pragma unroll
        for (int j = 0; j < 8; ++j) {
          union { fp16x2 h; uint u; } cv;
          cv.h = __builtin_amdgcn_cvt_pkrtz(xpv * zz[2 * j], xpv * zz[2 * j + 1]);
          ph.u[j] = cv.u;
        }
        *(uint4*)&zhi[zo0] = ph.qd[0];
        *(uint4*)&zhi[zo1] = ph.qd[1];
      }

      // Barrier B: z ds_writes visible; W(c) already retired above.
      asm volatile("s_waitcnt lgkmcnt(0)" ::: "memory");
      __builtin_amdgcn_sched_barrier(0);
      __builtin_amdgcn_s_barrier();
      __builtin_amdgcn_sched_barrier(0);

      // xn prefetch for step c+1 (issued under this step's MFMA phase).
      if (more) {
        const int qn = ((c + 1) & 3) * 32;
        xv0 = ((const float4*)(xrow + qn))[0];
        xv1 = ((const float4*)(xrow + qn))[1];
        xv2 = ((const float4*)(xrow + qn))[2];
        xv3 = ((const float4*)(xrow + qn))[3];
      }

      f16x8 Ah[4];
#pragma unroll
      for (int i = 0; i < 4; ++i) Ah[i] = *(const f16x8*)&zhi[aoff[i]];
#pragma unroll
      for (int j = 0; j < 4; ++j) {
        const f16x8 Bh = *(const f16x8*)&whi[cur][boff[j]];
        const f16x8 Bl = *(const f16x8*)&wlo[cur][boff[j]];
#pragma unroll
        for (int i = 0; i < 4; ++i)
          acc[i][j] = __builtin_amdgcn_mfma_f32_16x16x32_f16(Ah[i], Bh, acc[i][j], 0, 0, 0);
#pragma unroll
        for (int i = 0; i < 4; ++i)
          acc[i][j] = __builtin_amdgcn_mfma_f32_16x16x32_f16(Ah[i], Bl, acc[i][j], 0, 0, 0);
      }
    }
  }

#pragma unroll
  for (int i = 0; i < 4; ++i)
#pragma unroll
    for (int j = 0; j < 4; ++j) {
      const int row = n0 + wr + i * 16 + (l >> 4) * 4;
      const int col = h0 + wc + j * 16 + (l & 15);
#pragma unroll
      for (int r = 0; r < 4; ++r)
        atomicAdd(&xout[(size_t)(row + r) * HD + col], acc[i][j][r]);
    }
}

// ---------------------------------------------------------------------------
// K23: xt[k][n][d] = sum_h (x[n][h]+b[h]) * (Wthi+Wtlo)[k*64+d][h]
// 2-pass fp16 MFMA; bias+cvt fused in A-stage; u/v dots fused in epilogue.
// ---------------------------------------------------------------------------
__global__ __launch_bounds__(256) void k23_xt(
    const float* __restrict__ x, const float* __restrict__ bb,
    const f16* __restrict__ Wthi, const f16* __restrict__ Wtlo,
    const float* __restrict__ av, float* __restrict__ xt,
    float* __restrict__ ssrc, float* __restrict__ sdst) {
  __shared__ f16 ah[64 * 32];
  __shared__ f16 bh[128 * 32];
  __shared__ f16 bl[128 * 32];
  __shared__ float red1[2][64][17];
  __shared__ float red2[2][64][17];
  const int t = threadIdx.x;
  const int n0 = blockIdx.x * 64;
  const int c0 = blockIdx.y * 128;
  const int l = t & 63, w = t >> 6;
  const int wn = (w & 1) * 32, wcc = (w >> 1) * 64;

  int aoff[2], boff[4];
#pragma unroll
  for (int i = 0; i < 2; ++i) {
    const int row = wn + i * 16 + (l & 15);
    aoff[i] = row * 32 + (((l >> 4) ^ ((row ^ (row >> 2)) & 3)) * 8);
  }
#pragma unroll
  for (int j = 0; j < 4; ++j) {
    const int hr = wcc + j * 16 + (l & 15);
    boff[j] = hr * 32 + (((l >> 4) ^ ((hr ^ (hr >> 2)) & 3)) * 8);
  }

  f32x4 acc[2][4];
#pragma unroll
  for (int i = 0; i < 2; ++i)
#pragma unroll
    for (int j = 0; j < 4; ++j) acc[i][j] = (f32x4)0.f;

  for (int kc = 0; kc < HD; kc += 32) {
    __syncthreads();
    {  // A stage: read x fp32 + bias, cvt f16, store 16B (swizzled seg)
      const int row = t >> 2, sg = t & 3;
      const float* xr = &x[(size_t)(n0 + row) * HD + kc + sg * 8];
      const float4 xa = ((const float4*)xr)[0];
      const float4 xb = ((const float4*)xr)[1];
      const float4 ba = *(const float4*)&bb[kc + sg * 8];
      const float4 bv = *(const float4*)&bb[kc + sg * 8 + 4];
      f16x8 o;
      o[0] = (f16)(xa.x + ba.x); o[1] = (f16)(xa.y + ba.y);
      o[2] = (f16)(xa.z + ba.z); o[3] = (f16)(xa.w + ba.w);
      o[4] = (f16)(xb.x + bv.x); o[5] = (f16)(xb.y + bv.y);
      o[6] = (f16)(xb.z + bv.z); o[7] = (f16)(xb.w + bv.w);
      const int sgs = sg ^ ((row ^ (row >> 2)) & 3);
      *(f16x8*)&ah[row * 32 + sgs * 8] = o;
    }
#pragma unroll
    for (int g = 0; g < 2; ++g) {  // B stage: 128 cols x 4 segs = 512 slots
      const int slot = g * 256 + t;
      const int col = slot >> 2, ps = slot & 3;
      const int ls = ps ^ ((col ^ (col >> 2)) & 3);
      *(uint4*)&bh[col * 32 + ps * 8] =
          *(const uint4*)&Wthi[(size_t)(c0 + col) * HD + kc + ls * 8];
      *(uint4*)&bl[col * 32 + ps * 8] =
          *(const uint4*)&Wtlo[(size_t)(c0 + col) * HD + kc + ls * 8];
    }
    __syncthreads();
    f16x8 Af[2];
#pragma unroll
    for (int i = 0; i < 2; ++i) Af[i] = *(const f16x8*)&ah[aoff[i]];
#pragma unroll
    for (int j = 0; j < 4; ++j) {
      const f16x8 Bh = *(const f16x8*)&bh[boff[j]];
      const f16x8 Bl = *(const f16x8*)&bl[boff[j]];
#pragma unroll
      for (int i = 0; i < 2; ++i)
        acc[i][j] = __builtin_amdgcn_mfma_f32_16x16x32_f16(Af[i], Bh, acc[i][j], 0, 0, 0);
#pragma unroll
      for (int i = 0; i < 2; ++i)
        acc[i][j] = __builtin_amdgcn_mfma_f32_16x16x32_f16(Af[i], Bl, acc[i][j], 0, 0, 0);
    }
  }

  const int hh = w >> 1;
  const int khead = (c0 >> 6) + hh;
  float a1v[4], a2v[4];
#pragma unroll
  for (int j = 0; j < 4; ++j) {
    const int d = j * 16 + (l & 15);
    a1v[j] = av[khead * (2 * DD) + d];
    a2v[j] = av[khead * (2 * DD) + DD + d];
  }

#pragma unroll
  for (int i = 0; i < 2; ++i)
#pragma unroll
    for (int r = 0; r < 4; ++r) {
      const int rowl = wn + i * 16 + (l >> 4) * 4 + r;
      float p1 = 0.f, p2 = 0.f;
#pragma unroll
      for (int j = 0; j < 4; ++j) {
        p1 += acc[i][j][r] * a1v[j];
        p2 += acc[i][j][r] * a2v[j];
      }
      red1[hh][rowl][l & 15] = p1;
      red2[hh][rowl][l & 15] = p2;
    }

#pragma unroll
  for (int i = 0; i < 2; ++i)
#pragma unroll
    for (int j = 0; j < 4; ++j) {
      const int row = n0 + wn + i * 16 + (l >> 4) * 4;
      const int colg = c0 + wcc + j * 16 + (l & 15);
      const int k = colg >> 6, d = colg & 63;
#pragma unroll
      for (int r = 0; r < 4; ++r)
        xt[((size_t)(k * NN + row + r)) * DD + d] = acc[i][j][r];
    }

  __syncthreads();
  {
    const int hh2 = t >> 7;
    const int which = (t >> 6) & 1;
    const int row = t & 63;
    const float* rp = which ? &red2[hh2][row][0] : &red1[hh2][row][0];
    float s = 0.f;
#pragma unroll
    for (int g = 0; g < 16; ++g) s += rp[g];
    const int kk = (c0 >> 6) + hh2;
    if (which) sdst[kk * NN + n0 + row] = s;
    else ssrc[kk * NN + n0 + row] = s;
  }
}

// ---------------------------------------------------------------------------
// K4a: rank-and-scatter "sort" (exact total order via packed u64 keys).
// R11: grid (64,KH), 64 m/block, 4 threads per m each counting a 1024-wide
// j-quarter; partials summed in LDS. Bit-identical ranks.
// ---------------------------------------------------------------------------
__global__ __launch_bounds__(256) void k4_rank(
    const float* __restrict__ sdst, float* __restrict__ vsorted,
    int* __restrict__ perm) {
  __shared__ u64 kv[4096];
  __shared__ ushort pcnt[256];
  const int k = blockIdx.y, t = threadIdx.x;
  for (int i = t; i < 4096; i += 256) {
    const uint u = __float_as_uint(sdst[k * NN + i]);
    const uint key = (u & 0x80000000u) ? ~u : (u | 0x80000000u);
    kv[i] = ((u64)key << 32) | (uint)i;
  }
  __syncthreads();
  const int idx = t & 63;           // local m index (0..63)
  const int qtr = t >> 6;           // j-quarter this thread scans
  const u64 my = kv[blockIdx.x * 64 + idx];
  const int j0 = qtr * 1024;
  int cnt = 0;
#pragma unroll 16
  for (int j = 0; j < 1024; ++j) cnt += (kv[j0 + j] < my) ? 1 : 0;
  pcnt[t] = (ushort)cnt;
  __syncthreads();
  if (t < 64) {
    const int tot = (int)pcnt[t] + (int)pcnt[t + 64] + (int)pcnt[t + 128] +
                    (int)pcnt[t + 192];
    const u64 my2 = kv[blockIdx.x * 64 + t];
    const uint key = (uint)(my2 >> 32);
    const uint u = (key & 0x80000000u) ? (key ^ 0x80000000u) : ~key;
    vsorted[k * NN + tot] = __uint_as_float(u);
    perm[k * NN + tot] = (int)(my2 & 0xFFFFFFFFu);
  }
}

// ---------------------------------------------------------------------------
// K4b (R16): 256 threads / 4 waves per block (was 64/1). Wave w gathers and
// reduces rows 16w..16w+15; partials combined via LDS. Waves/CU 2 -> 8 for
// this latency-bound random gather. Only fp32 reassociation of the 64-row
// sum (4 partials) — noise far below the fp16-MFMA absmax floor.
// ---------------------------------------------------------------------------
__global__ __launch_bounds__(256) void k4b_chunksum(
    const float* __restrict__ vs, const int* __restrict__ perm,
    const float* __restrict__ xt, float* __restrict__ Chi, float* __restrict__ Clo) {
  __shared__ float rows[64][64];
  __shared__ float eh[64], el[64];
  __shared__ float ps[4][4][64];  // [stat][wave][col]
  const int c = blockIdx.x, k = blockIdx.y, t = threadIdx.x;
  const int base = k * NN + c * 64;
  if (t < 64) {
    const float v = vs[base + t];
    eh[t] = __expf(v);
    el[t] = __expf(0.2f * v);
  }
#pragma unroll
  for (int r = 0; r < 4; ++r) {
    const int i = r * 16 + (t >> 4);
    const int p = perm[base + i];
    *(float4*)&rows[i][(t & 15) * 4] =
        *(const float4*)&xt[((size_t)(k * NN + p)) * DD + (t & 15) * 4];
  }
  __syncthreads();
  const int w = t >> 6, col = t & 63;
  float shi = 0.f, slo = 0.f, whs = 0.f, wls = 0.f;
#pragma unroll
  for (int r = 0; r < 16; ++r) {
    const int i = w * 16 + r;
    const float val = rows[i][col];
    shi += eh[i] * val; slo += el[i] * val;
    whs += eh[i]; wls += el[i];
  }
  ps[0][w][col] = shi; ps[1][w][col] = slo;
  ps[2][w][col] = whs; ps[3][w][col] = wls;
  __syncthreads();
  if (t < 64) {
    const int cb = (k * 64 + c) * 65;
    Chi[cb + t] = ps[0][0][t] + ps[0][1][t] + ps[0][2][t] + ps[0][3][t];
    Clo[cb + t] = ps[1][0][t] + ps[1][1][t] + ps[1][2][t] + ps[1][3][t];
    if (t == 0) {
      Chi[cb + 64] = ps[2][0][0] + ps[2][1][0] + ps[2][2][0] + ps[2][3][0];
      Clo[cb + 64] = ps[3][0][0] + ps[3][1][0] + ps[3][2][0] + ps[3][3][0];
    }
  }
}

// ---------------------------------------------------------------------------
// K4d (R11): prefix+suffix merged into one 128-thread block (wave0 = prefix/
// Plo with el, wave1 = suffix/Phi with eh). Shares the rows[] gather and the
// chunk-sum staging. Per-output arithmetic and order identical.
// ---------------------------------------------------------------------------
__global__ __launch_bounds__(128) void k4d_expand(
    const float* __restrict__ vs, const int* __restrict__ perm,
    const float* __restrict__ xt, const float* __restrict__ Chi,
    const float* __restrict__ Clo, float* __restrict__ Phi,
    float* __restrict__ Plo) {
  __shared__ float schi[64 * 65];
  __shared__ float sclo[64 * 65];
  __shared__ float rows[64][64];
  __shared__ float eh[64], el[64];
  const int c = blockIdx.x, k = blockIdx.y, t = threadIdx.x;
  const int base = k * NN + c * 64;
  for (int idx = t; idx < 4160; idx += 128) {
    schi[idx] = Chi[k * 4160 + idx];
    sclo[idx] = Clo[k * 4160 + idx];
  }
  if (t < 64) {
    const float v = vs[base + t];
    eh[t] = __expf(v);
    el[t] = __expf(0.2f * v);
  }
#pragma unroll
  for (int r = 0; r < 8; ++r) {
    const int i = r * 8 + (t >> 4);
    const int p = perm[base + i];
    *(float4*)&rows[i][(t & 15) * 4] =
        *(const float4*)&xt[((size_t)(k * NN + p)) * DD + (t & 15) * 4];
  }
  __syncthreads();

  if (t < 64) {  // wave 0: prefix pass -> Plo
    const int tt = t;
    float run = 0.f, wrun = 0.f;
    for (int cc = 0; cc < c; ++cc) {
      run += sclo[cc * 65 + tt];
      wrun += sclo[cc * 65 + 64];
    }
    for (int i = 0; i < 64; ++i) {
      const size_t rb = ((size_t)(k * 4097) + c * 64 + i) * 65;
      Plo[rb + tt] = run;
      if (tt == 0) Plo[rb + 64] = wrun;
      run += el[i] * rows[i][tt];
      wrun += el[i];
    }
    if (c == 63) {
      const size_t rb = ((size_t)(k * 4097) + 4096) * 65;
      Plo[rb + tt] = run;
      if (tt == 0) Plo[rb + 64] = wrun;
    }
  } else {  // wave 1: suffix pass -> Phi
    const int tt = t - 64;
    float runS = 0.f, wrunS = 0.f;
    for (int cc = c + 1; cc < 64; ++cc) {
      runS += schi[cc * 65 + tt];
      wrunS += schi[cc * 65 + 64];
    }
    for (int i = 63; i >= 0; --i) {
      runS += eh[i] * rows[i][tt];
      wrunS += eh[i];
      const size_t rb = ((size_t)(k * 4097) + c * 64 + i) * 65;
      Phi[rb + tt] = runS;
      if (tt == 0) Phi[rb + 64] = wrunS;
    }
    if (c == 63) {
      const size_t rb = ((size_t)(k * 4097) + 4096) * 65;
      Phi[rb + tt] = 0.f;
      if (tt == 0) Phi[rb + 64] = 0.f;
    }
  }
}

// ---------------------------------------------------------------------------
// K6 (R11): 32 queries/block — verified optimum of the staging/parallelism
// trade (64q at 512 blocks = 2/CU regressed; 16q doubles staging traffic).
// ---------------------------------------------------------------------------
__global__ __launch_bounds__(256) void k6_final(
    const float* __restrict__ ssrc, const float* __restrict__ vsorted,
    const float* __restrict__ Phi, const float* __restrict__ Plo,
    float* __restrict__ out) {
  __shared__ float vsh[4096];
  __shared__ int posSh[32];
  const int t = threadIdx.x;
  const int q0 = blockIdx.x * 32;
  const int k = q0 >> 12;
  for (int idx = t; idx < 1024; idx += 256)
    *(float4*)&vsh[idx * 4] = *(const float4*)&vsorted[k * NN + idx * 4];
  __syncthreads();
  if (t < 32) {
    const float thr = -ssrc[q0 + t];
    int lo = 0, hi = 4096;
    while (lo < hi) {
      const int mid = (lo + hi) >> 1;
      if (vsh[mid] < thr) lo = mid + 1; else hi = mid;
    }
    posSh[t] = lo;
  }
  __syncthreads();
  const int d = t & 63;
#pragma unroll
  for (int qq = 0; qq < 8; ++qq) {
    const int ql = qq * 4 + (t >> 6);
    const int qi = q0 + ql;
    const int n = qi & 4095;
    const float u = ssrc[qi];
    const size_t rb = ((size_t)(k * 4097) + posSh[ql]) * 65;
    const float eu = __expf(u), el = __expf(0.2f * u);
    const float num = eu * Phi[rb + d] + el * Plo[rb + d];
    const float den = eu * Phi[rb + 64] + el * Plo[rb + 64];
    out[(size_t)n * (KH * DD) + k * DD + d] = tanhf(num / den);
  }
}

extern "C" void kernel_launch(void* const* d_in, const int* in_sizes, int n_in,
                              void* d_out, int out_size, void* d_ws, size_t ws_size,
                              hipStream_t stream) {
  const float* xp = (const float*)d_in[0];
  const float* xn = (const float*)d_in[1];
  const float* W = (const float*)d_in[2];
  const float* bb = (const float*)d_in[3];
  const float* Wt = (const float*)d_in[4];
  const float* av = (const float*)d_in[5];
  float* out = (float*)d_out;

  char* ws = (char*)d_ws;
  // Phi/Plo overlay the W splits (temporally disjoint).
  f16* Whi    = (f16*)(ws);                       // 8 MB
  f16* Wlo    = (f16*)(ws + 8388608);             // 8 MB
  float* Phi  = (float*)(ws);                     // 8.52 MB (overlay)
  float* Plo  = (float*)(ws + 8522240);           // 8.52 MB (overlay)
  float* x    = (float*)(ws + 17044480);          // 4 MB
  float* xt   = (float*)(ws + 21238784);          // 8 MB
  f16* Wthi   = (f16*)(ws + 31724544);            // 256 KB
  f16* Wtlo   = (f16*)(ws + 31986688);            // 256 KB
  float* ssrc = (float*)(ws + 32248832);          // 128 KB
  float* sdst = (float*)(ws + 32379904);          // 128 KB
  float* vsort= (float*)(ws + 32510976);          // 128 KB
  int*   perm = (int*)  (ws + 32642048);          // 128 KB
  float* Chi  = (float*)(ws + 32773120);          // 133 KB
  float* Clo  = (float*)(ws + 32906240);          // 133 KB -> ends ~33.0 MB

  k0_split2<<<(HD * PP * QQ + KH * DD * HD) / 1024, 256, 0, stream>>>(
      W, Wt, Whi, Wlo, Wthi, Wtlo, x);
  k1_bilinear<<<1024, 256, 0, stream>>>(xp, xn, Whi, Wlo, x);
  k23_xt<<<dim3(NN / 64, 4), 256, 0, stream>>>(x, bb, Wthi, Wtlo, av, xt, ssrc, sdst);
  k4_rank<<<dim3(64, KH), 256, 0, stream>>>(sdst, vsort, perm);
  k4b_chunksum<<<dim3(64, KH), 256, 0, stream>>>(vsort, perm, xt, Chi, Clo);
  k4d_expand<<<dim3(64, KH), 128, 0, stream>>>(vsort, perm, xt, Chi, Clo, Phi, Plo);
  k6_final<<<(KH * NN) / 32, 256, 0, stream>>>(ssrc, vsort, Phi, Plo, out);
}